// Round 1
// baseline (13289.006 us; speedup 1.0000x reference)
//
#include <hip/hip_runtime.h>

// Bidirectional 3-layer GRU encoder, wavefront-scheduled over (layer, time)
// anti-diagonals. 130 stage kernels; each stage computes up to 3 cells x 2
// directions with bf16 MFMA (fp32 accum), fp32 gate math, fp32 master h.
//
// T=128 B=512 D=300(pad 320) H=512, gates stacked [r,z,n] (3H rows of W).

typedef short bf16x8 __attribute__((ext_vector_type(8)));
typedef float f32x4 __attribute__((ext_vector_type(4)));
typedef unsigned short u16;

#define TT 128
#define BB 512
#define DD 300
#define DP 320
#define HH 512
#define G3 1536
#define NSTAGE (TT + 2)   // 130

__device__ __forceinline__ u16 f2b(float f) {
  union { float f; unsigned u; } v; v.f = f;
  unsigned r = (v.u + 0x7fffu + ((v.u >> 16) & 1u)) >> 16;
  return (u16)r;
}

__global__ void k_cvt(const float* __restrict__ in, u16* __restrict__ out, int n) {
  int i = blockIdx.x * 256 + threadIdx.x;
  if (i < n) out[i] = f2b(in[i]);
}

// row-major [rows][ic] f32 -> [rows][oc] bf16, zero-padded cols ic..oc
__global__ void k_cvt_pad(const float* __restrict__ in, u16* __restrict__ out,
                          int rows, int ic, int oc) {
  int i = blockIdx.x * 256 + threadIdx.x;
  if (i >= rows * oc) return;
  int r = i / oc, c = i - r * oc;
  out[i] = (c < ic) ? f2b(in[(size_t)r * ic + c]) : (u16)0;
}

struct StageParams {
  const u16* Xb;      // [TT][BB][DP] bf16
  const u16* Wih0b;   // [2][G3][DP]
  const u16* Whh0b;   // [2][G3][HH]
  const u16* Wihb;    // [2][2][G3][HH]  (dir, layer-1)
  const u16* Whhb;    // [2][2][G3][HH]
  float* hf0; float* hf1;   // parity buffers: [6 slots = dir*3+l][BB][HH] f32
  u16*   hb0; u16*   hb1;   // bf16 mirrors
  const float* bih[6];      // [dir*3 + l]
  const float* bhh[6];
};

// grid: 384 blocks = dir(2) x cell(3) x rowtile(8) x coltile(8); 256 threads.
// Wave w computes rows [rt*64+w*16, +16) x cols [ct*64, +64) of h_new.
__global__ __launch_bounds__(256, 2) void k_stage(int s, StageParams P) {
  int bid = blockIdx.x;
  int ct = bid & 7;
  int rt = (bid >> 3) & 7;
  int cell = (bid >> 6) % 3;
  int dir = bid / 192;
  int t = s - cell;
  if (t < 0 || t >= TT) return;

  int p = s & 1;  // read parity
  const float* hf_in  = p ? P.hf1 : P.hf0;
  float*       hf_out = p ? P.hf0 : P.hf1;
  const u16*   hb_in  = p ? P.hb1 : P.hb0;
  u16*         hb_out = p ? P.hb0 : P.hb1;

  int lane = threadIdx.x & 63;
  int w = threadIdx.x >> 6;
  int rbase = rt * 64 + w * 16;
  int cbase = ct * 64;
  int slot = dir * 3 + cell;

  // A operands (bf16): x-input and h-state; B operands: Wih, Whh rows ([N][K])
  const u16* Ah = hb_in + (size_t)slot * BB * HH;
  const u16* Ax; int lda_x; int kx;
  const u16* Bx; int ldb_x;
  if (cell == 0) {
    int tx = dir ? (TT - 1 - t) : t;
    Ax = P.Xb + (size_t)tx * BB * DP; lda_x = DP; kx = DP;
    Bx = P.Wih0b + (size_t)dir * G3 * DP; ldb_x = DP;
  } else {
    Ax = hb_in + (size_t)(slot - 1) * BB * HH; lda_x = HH; kx = HH;
    Bx = P.Wihb + (size_t)(dir * 2 + cell - 1) * G3 * HH; ldb_x = HH;
  }
  const u16* Bh = (cell == 0) ? (P.Whh0b + (size_t)dir * G3 * HH)
                              : (P.Whhb + (size_t)(dir * 2 + cell - 1) * G3 * HH);

  f32x4 acc_x[3][4] = {};   // gi accum, gate g, colfrag c
  f32x4 acc_h[3][4] = {};   // gh accum
  int am = lane & 15;             // A row / B col within fragment
  int koff = (lane >> 4) * 8;     // k offset within 32-chunk

  // gh = h @ Whh^T   (K = 512)
  {
    const u16* aph = Ah + (size_t)(rbase + am) * HH + koff;
    #pragma unroll 1
    for (int kc = 0; kc < HH; kc += 32) {
      bf16x8 a = *(const bf16x8*)(aph + kc);
      #pragma unroll
      for (int g = 0; g < 3; ++g) {
        #pragma unroll
        for (int c = 0; c < 4; ++c) {
          int n = g * HH + cbase + c * 16 + am;
          bf16x8 b = *(const bf16x8*)(Bh + (size_t)n * HH + koff + kc);
          acc_h[g][c] = __builtin_amdgcn_mfma_f32_16x16x32_bf16(a, b, acc_h[g][c], 0, 0, 0);
        }
      }
    }
  }
  // gi = x @ Wih^T   (K = 320 padded for layer 0, else 512)
  {
    const u16* apx = Ax + (size_t)(rbase + am) * lda_x + koff;
    #pragma unroll 1
    for (int kc = 0; kc < kx; kc += 32) {
      bf16x8 a = *(const bf16x8*)(apx + kc);
      #pragma unroll
      for (int g = 0; g < 3; ++g) {
        #pragma unroll
        for (int c = 0; c < 4; ++c) {
          int n = g * HH + cbase + c * 16 + am;
          bf16x8 b = *(const bf16x8*)(Bx + (size_t)n * ldb_x + koff + kc);
          acc_x[g][c] = __builtin_amdgcn_mfma_f32_16x16x32_bf16(a, b, acc_x[g][c], 0, 0, 0);
        }
      }
    }
  }

  // gates + state update (fp32)
  const float* bih = P.bih[slot];
  const float* bhh = P.bhh[slot];
  const float* hin  = hf_in  + (size_t)slot * BB * HH;
  float*       hout = hf_out + (size_t)slot * BB * HH;
  u16*         bout = hb_out + (size_t)slot * BB * HH;
  int r0 = rbase + (lane >> 4) * 4;   // C/D: col = lane&15, row = (lane>>4)*4+reg

  #pragma unroll
  for (int c = 0; c < 4; ++c) {
    int col = cbase + c * 16 + am;
    float bir = bih[col], biz = bih[HH + col], bin = bih[2 * HH + col];
    float bhr = bhh[col], bhz = bhh[HH + col], bhn = bhh[2 * HH + col];
    #pragma unroll
    for (int reg = 0; reg < 4; ++reg) {
      int row = r0 + reg;
      float ir = acc_x[0][c][reg] + bir;
      float hr = acc_h[0][c][reg] + bhr;
      float iz = acc_x[1][c][reg] + biz;
      float hz = acc_h[1][c][reg] + bhz;
      float in_ = acc_x[2][c][reg] + bin;
      float hn = acc_h[2][c][reg] + bhn;
      float rg = 1.f / (1.f + __expf(-(ir + hr)));
      float zg = 1.f / (1.f + __expf(-(iz + hz)));
      float ng = tanhf(in_ + rg * hn);
      float hp = hin[(size_t)row * HH + col];
      float hv = (1.f - zg) * ng + zg * hp;
      hout[(size_t)row * HH + col] = hv;
      bout[(size_t)row * HH + col] = f2b(hv);
    }
  }
}

struct HeadParams {
  const u16* Wmub;   // [HH][2*HH] bf16
  const u16* Wlvb;
  const u16* hb0;    // final states live in parity-0 buffer (stage 129 writes it)
  const float* bmu; const float* blv;
  float* out;        // [2][BB][HH]: mu then logvar
};

// grid: 128 blocks = which(2) x rowtile(8) x coltile(8)
__global__ __launch_bounds__(256, 2) void k_head(HeadParams P) {
  int bid = blockIdx.x;
  int ct = bid & 7, rt = (bid >> 3) & 7, which = bid >> 6;
  int lane = threadIdx.x & 63, w = threadIdx.x >> 6;
  int rbase = rt * 64 + w * 16, cbase = ct * 64;
  const u16* Wb = which ? P.Wlvb : P.Wmub;
  const float* bias = which ? P.blv : P.bmu;
  const u16* Afw = P.hb0 + (size_t)2 * BB * HH;   // slot 2 = fw layer2
  const u16* Abw = P.hb0 + (size_t)5 * BB * HH;   // slot 5 = bw layer2
  int am = lane & 15, koff = (lane >> 4) * 8;
  f32x4 acc[4] = {};
  const u16* a0 = Afw + (size_t)(rbase + am) * HH + koff;
  const u16* a1 = Abw + (size_t)(rbase + am) * HH + koff;
  #pragma unroll 1
  for (int kc = 0; kc < HH; kc += 32) {
    bf16x8 a = *(const bf16x8*)(a0 + kc);
    #pragma unroll
    for (int c = 0; c < 4; ++c) {
      int n = cbase + c * 16 + am;
      bf16x8 b = *(const bf16x8*)(Wb + (size_t)n * (2 * HH) + koff + kc);
      acc[c] = __builtin_amdgcn_mfma_f32_16x16x32_bf16(a, b, acc[c], 0, 0, 0);
    }
  }
  #pragma unroll 1
  for (int kc = 0; kc < HH; kc += 32) {
    bf16x8 a = *(const bf16x8*)(a1 + kc);
    #pragma unroll
    for (int c = 0; c < 4; ++c) {
      int n = cbase + c * 16 + am;
      bf16x8 b = *(const bf16x8*)(Wb + (size_t)n * (2 * HH) + HH + koff + kc);
      acc[c] = __builtin_amdgcn_mfma_f32_16x16x32_bf16(a, b, acc[c], 0, 0, 0);
    }
  }
  float* out = P.out + (size_t)which * BB * HH;
  int r0 = rbase + (lane >> 4) * 4;
  #pragma unroll
  for (int c = 0; c < 4; ++c) {
    int col = cbase + c * 16 + am;
    float bv = bias[col];
    #pragma unroll
    for (int reg = 0; reg < 4; ++reg) {
      out[(size_t)(r0 + reg) * HH + col] = acc[c][reg] + bv;
    }
  }
}

extern "C" void kernel_launch(void* const* d_in, const int* in_sizes, int n_in,
                              void* d_out, int out_size, void* d_ws, size_t ws_size,
                              hipStream_t stream) {
  (void)in_sizes; (void)n_in; (void)ws_size;
  char* ws = (char*)d_ws;
  size_t off = 0;
  auto alloc = [&](size_t bytes) {
    char* q = ws + off;
    off += (bytes + 255) & ~(size_t)255;
    return q;
  };
  u16* Xb    = (u16*)alloc((size_t)TT * BB * DP * 2);
  u16* Wih0b = (u16*)alloc((size_t)2 * G3 * DP * 2);
  u16* Whh0b = (u16*)alloc((size_t)2 * G3 * HH * 2);
  u16* Wihb  = (u16*)alloc((size_t)4 * G3 * HH * 2);
  u16* Whhb  = (u16*)alloc((size_t)4 * G3 * HH * 2);
  u16* Wmub  = (u16*)alloc((size_t)HH * 2 * HH * 2);
  u16* Wlvb  = (u16*)alloc((size_t)HH * 2 * HH * 2);
  float* hf  = (float*)alloc((size_t)2 * 6 * BB * HH * 4);
  u16*   hb  = (u16*)alloc((size_t)2 * 6 * BB * HH * 2);

  const float* X = (const float*)d_in[0];

  // zero h state (both parities, f32 + bf16)
  hipMemsetAsync(hf, 0, (size_t)2 * 6 * BB * HH * 4, stream);
  hipMemsetAsync(hb, 0, (size_t)2 * 6 * BB * HH * 2, stream);

  // convert inputs to bf16 workspace
  {
    int n = TT * BB * DP;
    k_cvt_pad<<<(n + 255) / 256, 256, 0, stream>>>(X, Xb, TT * BB, DD, DP);
    int nw0 = G3 * DP;
    k_cvt_pad<<<(nw0 + 255) / 256, 256, 0, stream>>>((const float*)d_in[2],  Wih0b,                 G3, DD, DP);
    k_cvt_pad<<<(nw0 + 255) / 256, 256, 0, stream>>>((const float*)d_in[10], Wih0b + (size_t)G3 * DP, G3, DD, DP);
    int n1 = G3 * HH;
    k_cvt<<<(n1 + 255) / 256, 256, 0, stream>>>((const float*)d_in[3],  Whh0b,      n1);
    k_cvt<<<(n1 + 255) / 256, 256, 0, stream>>>((const float*)d_in[11], Whh0b + n1, n1);
    int n2 = 2 * G3 * HH;
    k_cvt<<<(n2 + 255) / 256, 256, 0, stream>>>((const float*)d_in[6],  Wihb,      n2);
    k_cvt<<<(n2 + 255) / 256, 256, 0, stream>>>((const float*)d_in[14], Wihb + n2, n2);
    k_cvt<<<(n2 + 255) / 256, 256, 0, stream>>>((const float*)d_in[7],  Whhb,      n2);
    k_cvt<<<(n2 + 255) / 256, 256, 0, stream>>>((const float*)d_in[15], Whhb + n2, n2);
    int n3 = HH * 2 * HH;
    k_cvt<<<(n3 + 255) / 256, 256, 0, stream>>>((const float*)d_in[18], Wmub, n3);
    k_cvt<<<(n3 + 255) / 256, 256, 0, stream>>>((const float*)d_in[20], Wlvb, n3);
  }

  StageParams SP;
  SP.Xb = Xb; SP.Wih0b = Wih0b; SP.Whh0b = Whh0b; SP.Wihb = Wihb; SP.Whhb = Whhb;
  SP.hf0 = hf;                       SP.hf1 = hf + (size_t)6 * BB * HH;
  SP.hb0 = hb;                       SP.hb1 = hb + (size_t)6 * BB * HH;
  SP.bih[0] = (const float*)d_in[4];
  SP.bih[1] = (const float*)d_in[8];
  SP.bih[2] = (const float*)d_in[8] + G3;
  SP.bih[3] = (const float*)d_in[12];
  SP.bih[4] = (const float*)d_in[16];
  SP.bih[5] = (const float*)d_in[16] + G3;
  SP.bhh[0] = (const float*)d_in[5];
  SP.bhh[1] = (const float*)d_in[9];
  SP.bhh[2] = (const float*)d_in[9] + G3;
  SP.bhh[3] = (const float*)d_in[13];
  SP.bhh[4] = (const float*)d_in[17];
  SP.bhh[5] = (const float*)d_in[17] + G3;

  for (int s = 0; s < NSTAGE; ++s) {
    k_stage<<<384, 256, 0, stream>>>(s, SP);
  }

  HeadParams HP;
  HP.Wmub = Wmub; HP.Wlvb = Wlvb; HP.hb0 = hb;
  HP.bmu = (const float*)d_in[19]; HP.blv = (const float*)d_in[21];
  HP.out = (float*)d_out;
  k_head<<<128, 256, 0, stream>>>(HP);
}

// Round 2
// 5383.414 us; speedup vs baseline: 2.4685x; 2.4685x over previous
//
#include <hip/hip_runtime.h>

// Bidirectional 3-layer GRU encoder, wavefront-scheduled over (layer, time)
// anti-diagonals. 130 stage kernels; each stage computes up to 3 cells x 2
// directions with bf16 MFMA (fp32 accum), fp32 gate math, fp32 master h.
//
// Round 2: LDS-staged GEMM per stage. Block = 64 batch-rows x 192 gate-cols
// (= 64 H-cols x 3 gates), 2 waves x (32 rows x 12 col-frags), BK=64 with
// XOR-swizzled LDS (linear dest via global_load_lds + pre-swizzled source),
// double-buffered 2-phase pipeline. Grid 384 = 6 cell-dirs x 8 mt x 8 ht;
// bid%8==ht keeps each weight slice on one XCD's L2.

typedef short bf16x8 __attribute__((ext_vector_type(8)));
typedef float f32x4 __attribute__((ext_vector_type(4)));
typedef unsigned short u16;

#define TT 128
#define BB 512
#define DD 300
#define DP 320
#define HH 512
#define G3 1536
#define NSTAGE (TT + 2)   // 130

__device__ __forceinline__ u16 f2b(float f) {
  union { float f; unsigned u; } v; v.f = f;
  unsigned r = (v.u + 0x7fffu + ((v.u >> 16) & 1u)) >> 16;
  return (u16)r;
}

__global__ void k_cvt(const float* __restrict__ in, u16* __restrict__ out, int n) {
  int i = blockIdx.x * 256 + threadIdx.x;
  if (i < n) out[i] = f2b(in[i]);
}

// row-major [rows][ic] f32 -> [rows][oc] bf16, zero-padded cols ic..oc
__global__ void k_cvt_pad(const float* __restrict__ in, u16* __restrict__ out,
                          int rows, int ic, int oc) {
  int i = blockIdx.x * 256 + threadIdx.x;
  if (i >= rows * oc) return;
  int r = i / oc, c = i - r * oc;
  out[i] = (c < ic) ? f2b(in[(size_t)r * ic + c]) : (u16)0;
}

struct StageParams {
  const u16* Xb;      // [TT][BB][DP] bf16
  const u16* Wih0b;   // [2][G3][DP]
  const u16* Whh0b;   // [2][G3][HH]
  const u16* Wihb;    // [2][2][G3][HH]  (dir, layer-1)
  const u16* Whhb;    // [2][2][G3][HH]
  float* hf0; float* hf1;   // parity buffers: [6 slots = dir*3+l][BB][HH] f32
  u16*   hb0; u16*   hb1;   // bf16 mirrors
  const float* bih[6];
  const float* bhh[6];
};

__device__ __forceinline__ void gld_lds16(const u16* g, u16* l) {
  __builtin_amdgcn_global_load_lds(
      (const __attribute__((address_space(1))) unsigned int*)g,
      (__attribute__((address_space(3))) unsigned int*)l, 16, 0, 0);
}

// one K=64 chunk of MFMA from swizzled LDS tiles
__device__ __forceinline__ void do_chunk(const u16* __restrict__ As,
                                         const u16* __restrict__ Bs,
                                         int w, int am, int kq,
                                         f32x4 (&rs)[2][4], f32x4 (&zs)[2][4],
                                         f32x4 (&nn)[2][4]) {
  bf16x8 a[2][2];
  #pragma unroll
  for (int fr = 0; fr < 2; ++fr) {
    int row = w * 32 + fr * 16 + am;
    #pragma unroll
    for (int k = 0; k < 2; ++k) {
      int sl = (k * 4 + kq) ^ (row & 7);
      a[fr][k] = *(const bf16x8*)(As + row * 64 + sl * 8);
    }
  }
  #pragma unroll
  for (int hc = 0; hc < 4; ++hc) {
    #pragma unroll
    for (int k = 0; k < 2; ++k) {
      int r0 = 0 * 64 + hc * 16 + am;
      int r1 = 1 * 64 + hc * 16 + am;
      int r2 = 2 * 64 + hc * 16 + am;
      int sl0 = (k * 4 + kq) ^ (r0 & 7);
      int sl1 = (k * 4 + kq) ^ (r1 & 7);
      int sl2 = (k * 4 + kq) ^ (r2 & 7);
      bf16x8 b0 = *(const bf16x8*)(Bs + r0 * 64 + sl0 * 8);
      bf16x8 b1 = *(const bf16x8*)(Bs + r1 * 64 + sl1 * 8);
      bf16x8 b2 = *(const bf16x8*)(Bs + r2 * 64 + sl2 * 8);
      rs[0][hc] = __builtin_amdgcn_mfma_f32_16x16x32_bf16(a[0][k], b0, rs[0][hc], 0, 0, 0);
      rs[1][hc] = __builtin_amdgcn_mfma_f32_16x16x32_bf16(a[1][k], b0, rs[1][hc], 0, 0, 0);
      zs[0][hc] = __builtin_amdgcn_mfma_f32_16x16x32_bf16(a[0][k], b1, zs[0][hc], 0, 0, 0);
      zs[1][hc] = __builtin_amdgcn_mfma_f32_16x16x32_bf16(a[1][k], b1, zs[1][hc], 0, 0, 0);
      nn[0][hc] = __builtin_amdgcn_mfma_f32_16x16x32_bf16(a[0][k], b2, nn[0][hc], 0, 0, 0);
      nn[1][hc] = __builtin_amdgcn_mfma_f32_16x16x32_bf16(a[1][k], b2, nn[1][hc], 0, 0, 0);
    }
  }
}

// grid: 384 blocks = cd(6) x mt(8) x ht(8); 128 threads (2 waves).
__global__ __launch_bounds__(128, 2) void k_stage(int s, StageParams P) {
  __shared__ u16 AsS[2][64 * 64];    // [rows 64][BK 64] x dbuf   (16 KB)
  __shared__ u16 BsS[2][192 * 64];   // [gaterows 192][BK 64] x dbuf (48 KB)

  int bid = blockIdx.x;
  int ht = bid & 7;
  int mt = (bid >> 3) & 7;
  int cd = bid >> 6;             // 0..5
  int dir = cd / 3, cell = cd % 3;
  int t = s - cell;
  if (t < 0 || t >= TT) return;

  int p = s & 1;  // read parity
  const float* hf_in  = p ? P.hf1 : P.hf0;
  float*       hf_out = p ? P.hf0 : P.hf1;
  const u16*   hb_in  = p ? P.hb1 : P.hb0;
  u16*         hb_out = p ? P.hb0 : P.hb1;

  int lane = threadIdx.x & 63;
  int w = threadIdx.x >> 6;      // 0..1
  int am = lane & 15;
  int kq = lane >> 4;            // 0..3
  int slot = dir * 3 + cell;
  int hcol0 = ht * 64;
  int row0g = mt * 64;

  // operand bases (row offset mt*64 folded into A pointers)
  const char* Ah_ = (const char*)(hb_in + (size_t)slot * BB * HH + (size_t)row0g * HH);
  const char* Ax_; size_t ldax2; const char* Bx_; size_t ldbx2;
  if (cell == 0) {
    int tx = dir ? (TT - 1 - t) : t;
    Ax_ = (const char*)(P.Xb + ((size_t)tx * BB + row0g) * DP); ldax2 = DP * 2;
    Bx_ = (const char*)(P.Wih0b + (size_t)dir * G3 * DP);       ldbx2 = DP * 2;
  } else {
    Ax_ = (const char*)(hb_in + (size_t)(slot - 1) * BB * HH + (size_t)row0g * HH); ldax2 = HH * 2;
    Bx_ = (const char*)(P.Wihb + (size_t)(dir * 2 + cell - 1) * G3 * HH);           ldbx2 = HH * 2;
  }
  const char* Bh_ = (const char*)((cell == 0) ? (P.Whh0b + (size_t)dir * G3 * HH)
                                              : (P.Whhb + (size_t)(dir * 2 + cell - 1) * G3 * HH));

  int nxc = (cell == 0) ? 5 : 8;    // x-seg K64 chunks (320 or 512)
  int NC = 8 + nxc;

  // stage chunk ci into LDS buffer pb (linear dest, inverse-swizzled source)
  auto stage = [&](int ci, int pb) {
    const char* Ag; size_t la2; const char* Bg; size_t lb2; int kcb;
    if (ci < 8) { Ag = Ah_; la2 = HH * 2; Bg = Bh_; lb2 = HH * 2; kcb = ci * 128; }
    else        { Ag = Ax_; la2 = ldax2;  Bg = Bx_; lb2 = ldbx2;  kcb = (ci - 8) * 128; }
    u16* Ad = &AsS[pb][0];
    u16* Bd = &BsS[pb][0];
    int tid = threadIdx.x;
    #pragma unroll
    for (int j = 0; j < 4; ++j) {          // A: 512 16B units
      int u = tid + j * 128;
      int row = u >> 3, sl = u & 7;
      int scol = ((sl ^ (row & 7)) << 4);
      gld_lds16((const u16*)(Ag + (size_t)row * la2 + kcb + scol), Ad + u * 8);
    }
    #pragma unroll
    for (int j = 0; j < 12; ++j) {         // B: 1536 16B units (192 rows)
      int u = tid + j * 128;
      int g = u >> 9, rr = (u >> 3) & 63, sl = u & 7;
      int scol = ((sl ^ (rr & 7)) << 4);
      gld_lds16((const u16*)(Bg + (size_t)(g * HH + hcol0 + rr) * lb2 + kcb + scol),
                Bd + u * 8);
    }
  };

  f32x4 rs[2][4] = {}, zs[2][4] = {}, nx[2][4] = {}, nh[2][4] = {};

  stage(0, 0);
  __syncthreads();
  int cur = 0;
  for (int ci = 0; ci < NC; ++ci) {
    if (ci + 1 < NC) stage(ci + 1, cur ^ 1);
    if (ci < 8) do_chunk(&AsS[cur][0], &BsS[cur][0], w, am, kq, rs, zs, nh);
    else        do_chunk(&AsS[cur][0], &BsS[cur][0], w, am, kq, rs, zs, nx);
    __syncthreads();   // drains vmcnt(0): chunk ci+1's loads have landed
    cur ^= 1;
  }

  // gates + state update (fp32)
  const float* bihp = P.bih[slot];
  const float* bhhp = P.bhh[slot];
  const float* hin  = hf_in  + (size_t)slot * BB * HH;
  float*       hout = hf_out + (size_t)slot * BB * HH;
  u16*         bout = hb_out + (size_t)slot * BB * HH;

  #pragma unroll
  for (int hc = 0; hc < 4; ++hc) {
    int col = hcol0 + hc * 16 + am;
    float bir = bihp[col],          bhr = bhhp[col];
    float biz = bihp[HH + col],     bhz = bhhp[HH + col];
    float bin = bihp[2 * HH + col], bhn = bhhp[2 * HH + col];
    #pragma unroll
    for (int fr = 0; fr < 2; ++fr) {
      #pragma unroll
      for (int reg = 0; reg < 4; ++reg) {
        int row = row0g + w * 32 + fr * 16 + kq * 4 + reg;
        float rg = 1.f / (1.f + __expf(-(rs[fr][hc][reg] + bir + bhr)));
        float zg = 1.f / (1.f + __expf(-(zs[fr][hc][reg] + biz + bhz)));
        float ng = tanhf(nx[fr][hc][reg] + bin + rg * (nh[fr][hc][reg] + bhn));
        float hp = hin[(size_t)row * HH + col];
        float hv = (1.f - zg) * ng + zg * hp;
        hout[(size_t)row * HH + col] = hv;
        bout[(size_t)row * HH + col] = f2b(hv);
      }
    }
  }
}

struct HeadParams {
  const u16* Wmub;   // [HH][2*HH] bf16
  const u16* Wlvb;
  const u16* hb0;    // final states live in parity-0 buffer (stage 129 writes it)
  const float* bmu; const float* blv;
  float* out;        // [2][BB][HH]: mu then logvar
};

// grid: 128 blocks = which(2) x rowtile(8) x coltile(8)
__global__ __launch_bounds__(256, 2) void k_head(HeadParams P) {
  int bid = blockIdx.x;
  int ct = bid & 7, rt = (bid >> 3) & 7, which = bid >> 6;
  int lane = threadIdx.x & 63, w = threadIdx.x >> 6;
  int rbase = rt * 64 + w * 16, cbase = ct * 64;
  const u16* Wb = which ? P.Wlvb : P.Wmub;
  const float* bias = which ? P.blv : P.bmu;
  const u16* Afw = P.hb0 + (size_t)2 * BB * HH;   // slot 2 = fw layer2
  const u16* Abw = P.hb0 + (size_t)5 * BB * HH;   // slot 5 = bw layer2
  int am = lane & 15, koff = (lane >> 4) * 8;
  f32x4 acc[4] = {};
  const u16* a0 = Afw + (size_t)(rbase + am) * HH + koff;
  const u16* a1 = Abw + (size_t)(rbase + am) * HH + koff;
  #pragma unroll 1
  for (int kc = 0; kc < HH; kc += 32) {
    bf16x8 a = *(const bf16x8*)(a0 + kc);
    #pragma unroll
    for (int c = 0; c < 4; ++c) {
      int n = cbase + c * 16 + am;
      bf16x8 b = *(const bf16x8*)(Wb + (size_t)n * (2 * HH) + koff + kc);
      acc[c] = __builtin_amdgcn_mfma_f32_16x16x32_bf16(a, b, acc[c], 0, 0, 0);
    }
  }
  #pragma unroll 1
  for (int kc = 0; kc < HH; kc += 32) {
    bf16x8 a = *(const bf16x8*)(a1 + kc);
    #pragma unroll
    for (int c = 0; c < 4; ++c) {
      int n = cbase + c * 16 + am;
      bf16x8 b = *(const bf16x8*)(Wb + (size_t)n * (2 * HH) + HH + koff + kc);
      acc[c] = __builtin_amdgcn_mfma_f32_16x16x32_bf16(a, b, acc[c], 0, 0, 0);
    }
  }
  float* out = P.out + (size_t)which * BB * HH;
  int r0 = rbase + (lane >> 4) * 4;
  #pragma unroll
  for (int c = 0; c < 4; ++c) {
    int col = cbase + c * 16 + am;
    float bv = bias[col];
    #pragma unroll
    for (int reg = 0; reg < 4; ++reg) {
      out[(size_t)(r0 + reg) * HH + col] = acc[c][reg] + bv;
    }
  }
}

extern "C" void kernel_launch(void* const* d_in, const int* in_sizes, int n_in,
                              void* d_out, int out_size, void* d_ws, size_t ws_size,
                              hipStream_t stream) {
  (void)in_sizes; (void)n_in; (void)ws_size;
  char* ws = (char*)d_ws;
  size_t off = 0;
  auto alloc = [&](size_t bytes) {
    char* q = ws + off;
    off += (bytes + 255) & ~(size_t)255;
    return q;
  };
  u16* Xb    = (u16*)alloc((size_t)TT * BB * DP * 2);
  u16* Wih0b = (u16*)alloc((size_t)2 * G3 * DP * 2);
  u16* Whh0b = (u16*)alloc((size_t)2 * G3 * HH * 2);
  u16* Wihb  = (u16*)alloc((size_t)4 * G3 * HH * 2);
  u16* Whhb  = (u16*)alloc((size_t)4 * G3 * HH * 2);
  u16* Wmub  = (u16*)alloc((size_t)HH * 2 * HH * 2);
  u16* Wlvb  = (u16*)alloc((size_t)HH * 2 * HH * 2);
  float* hf  = (float*)alloc((size_t)2 * 6 * BB * HH * 4);
  u16*   hb  = (u16*)alloc((size_t)2 * 6 * BB * HH * 2);

  const float* X = (const float*)d_in[0];

  hipMemsetAsync(hf, 0, (size_t)2 * 6 * BB * HH * 4, stream);
  hipMemsetAsync(hb, 0, (size_t)2 * 6 * BB * HH * 2, stream);

  {
    int n = TT * BB * DP;
    k_cvt_pad<<<(n + 255) / 256, 256, 0, stream>>>(X, Xb, TT * BB, DD, DP);
    int nw0 = G3 * DP;
    k_cvt_pad<<<(nw0 + 255) / 256, 256, 0, stream>>>((const float*)d_in[2],  Wih0b,                   G3, DD, DP);
    k_cvt_pad<<<(nw0 + 255) / 256, 256, 0, stream>>>((const float*)d_in[10], Wih0b + (size_t)G3 * DP, G3, DD, DP);
    int n1 = G3 * HH;
    k_cvt<<<(n1 + 255) / 256, 256, 0, stream>>>((const float*)d_in[3],  Whh0b,      n1);
    k_cvt<<<(n1 + 255) / 256, 256, 0, stream>>>((const float*)d_in[11], Whh0b + n1, n1);
    int n2 = 2 * G3 * HH;
    k_cvt<<<(n2 + 255) / 256, 256, 0, stream>>>((const float*)d_in[6],  Wihb,      n2);
    k_cvt<<<(n2 + 255) / 256, 256, 0, stream>>>((const float*)d_in[14], Wihb + n2, n2);
    k_cvt<<<(n2 + 255) / 256, 256, 0, stream>>>((const float*)d_in[7],  Whhb,      n2);
    k_cvt<<<(n2 + 255) / 256, 256, 0, stream>>>((const float*)d_in[15], Whhb + n2, n2);
    int n3 = HH * 2 * HH;
    k_cvt<<<(n3 + 255) / 256, 256, 0, stream>>>((const float*)d_in[18], Wmub, n3);
    k_cvt<<<(n3 + 255) / 256, 256, 0, stream>>>((const float*)d_in[20], Wlvb, n3);
  }

  StageParams SP;
  SP.Xb = Xb; SP.Wih0b = Wih0b; SP.Whh0b = Whh0b; SP.Wihb = Wihb; SP.Whhb = Whhb;
  SP.hf0 = hf;                       SP.hf1 = hf + (size_t)6 * BB * HH;
  SP.hb0 = hb;                       SP.hb1 = hb + (size_t)6 * BB * HH;
  SP.bih[0] = (const float*)d_in[4];
  SP.bih[1] = (const float*)d_in[8];
  SP.bih[2] = (const float*)d_in[8] + G3;
  SP.bih[3] = (const float*)d_in[12];
  SP.bih[4] = (const float*)d_in[16];
  SP.bih[5] = (const float*)d_in[16] + G3;
  SP.bhh[0] = (const float*)d_in[5];
  SP.bhh[1] = (const float*)d_in[9];
  SP.bhh[2] = (const float*)d_in[9] + G3;
  SP.bhh[3] = (const float*)d_in[13];
  SP.bhh[4] = (const float*)d_in[17];
  SP.bhh[5] = (const float*)d_in[17] + G3;

  for (int s = 0; s < NSTAGE; ++s) {
    k_stage<<<384, 128, 0, stream>>>(s, SP);
  }

  HeadParams HP;
  HP.Wmub = Wmub; HP.Wlvb = Wlvb; HP.hb0 = hb;
  HP.bmu = (const float*)d_in[19]; HP.blv = (const float*)d_in[21];
  HP.out = (float*)d_out;
  k_head<<<128, 256, 0, stream>>>(HP);
}

// Round 3
// 5283.728 us; speedup vs baseline: 2.5151x; 1.0189x over previous
//
#include <hip/hip_runtime.h>

// Bidirectional 3-layer GRU encoder, wavefront-scheduled over (layer, time)
// anti-diagonals. 130 stage kernels; each stage computes up to 3 cells x 2
// directions with bf16 MFMA (fp32 accum), fp32 gate math, fp32 master h.
//
// Round 3: fix the global_load_lds waterfall — LDS destination must be
// WAVE-UNIFORM (base + lane*16 implicit). Round 2 passed a per-lane LDS
// pointer, causing the compiler to serialize every staging instruction.
// Same tiling as round 2: block = 64 batch-rows x 192 gate-cols, 2 waves,
// BK=64, XOR-swizzled LDS (swizzle applied to the global source column),
// double-buffered 2-phase pipeline. Grid 384 = 6 cell-dirs x 8 mt x 8 ht.

typedef short bf16x8 __attribute__((ext_vector_type(8)));
typedef float f32x4 __attribute__((ext_vector_type(4)));
typedef unsigned short u16;

#define TT 128
#define BB 512
#define DD 300
#define DP 320
#define HH 512
#define G3 1536
#define NSTAGE (TT + 2)   // 130

__device__ __forceinline__ u16 f2b(float f) {
  union { float f; unsigned u; } v; v.f = f;
  unsigned r = (v.u + 0x7fffu + ((v.u >> 16) & 1u)) >> 16;
  return (u16)r;
}

__global__ void k_cvt(const float* __restrict__ in, u16* __restrict__ out, int n) {
  int i = blockIdx.x * 256 + threadIdx.x;
  if (i < n) out[i] = f2b(in[i]);
}

// row-major [rows][ic] f32 -> [rows][oc] bf16, zero-padded cols ic..oc
__global__ void k_cvt_pad(const float* __restrict__ in, u16* __restrict__ out,
                          int rows, int ic, int oc) {
  int i = blockIdx.x * 256 + threadIdx.x;
  if (i >= rows * oc) return;
  int r = i / oc, c = i - r * oc;
  out[i] = (c < ic) ? f2b(in[(size_t)r * ic + c]) : (u16)0;
}

struct StageParams {
  const u16* Xb;      // [TT][BB][DP] bf16
  const u16* Wih0b;   // [2][G3][DP]
  const u16* Whh0b;   // [2][G3][HH]
  const u16* Wihb;    // [2][2][G3][HH]  (dir, layer-1)
  const u16* Whhb;    // [2][2][G3][HH]
  float* hf0; float* hf1;   // parity buffers: [6 slots = dir*3+l][BB][HH] f32
  u16*   hb0; u16*   hb1;   // bf16 mirrors
  const float* bih[6];
  const float* bhh[6];
};

__device__ __forceinline__ void gld_lds16(const u16* g, u16* l) {
  __builtin_amdgcn_global_load_lds(
      (const __attribute__((address_space(1))) unsigned int*)g,
      (__attribute__((address_space(3))) unsigned int*)l, 16, 0, 0);
}

// one K=64 chunk of MFMA from swizzled LDS tiles
__device__ __forceinline__ void do_chunk(const u16* __restrict__ As,
                                         const u16* __restrict__ Bs,
                                         int w, int am, int kq,
                                         f32x4 (&rs)[2][4], f32x4 (&zs)[2][4],
                                         f32x4 (&nn)[2][4]) {
  bf16x8 a[2][2];
  #pragma unroll
  for (int fr = 0; fr < 2; ++fr) {
    int row = w * 32 + fr * 16 + am;
    #pragma unroll
    for (int k = 0; k < 2; ++k) {
      int sl = (k * 4 + kq) ^ (row & 7);
      a[fr][k] = *(const bf16x8*)(As + row * 64 + sl * 8);
    }
  }
  #pragma unroll
  for (int hc = 0; hc < 4; ++hc) {
    #pragma unroll
    for (int k = 0; k < 2; ++k) {
      int r0 = 0 * 64 + hc * 16 + am;
      int r1 = 1 * 64 + hc * 16 + am;
      int r2 = 2 * 64 + hc * 16 + am;
      int sl0 = (k * 4 + kq) ^ (r0 & 7);
      int sl1 = (k * 4 + kq) ^ (r1 & 7);
      int sl2 = (k * 4 + kq) ^ (r2 & 7);
      bf16x8 b0 = *(const bf16x8*)(Bs + r0 * 64 + sl0 * 8);
      bf16x8 b1 = *(const bf16x8*)(Bs + r1 * 64 + sl1 * 8);
      bf16x8 b2 = *(const bf16x8*)(Bs + r2 * 64 + sl2 * 8);
      rs[0][hc] = __builtin_amdgcn_mfma_f32_16x16x32_bf16(a[0][k], b0, rs[0][hc], 0, 0, 0);
      rs[1][hc] = __builtin_amdgcn_mfma_f32_16x16x32_bf16(a[1][k], b0, rs[1][hc], 0, 0, 0);
      zs[0][hc] = __builtin_amdgcn_mfma_f32_16x16x32_bf16(a[0][k], b1, zs[0][hc], 0, 0, 0);
      zs[1][hc] = __builtin_amdgcn_mfma_f32_16x16x32_bf16(a[1][k], b1, zs[1][hc], 0, 0, 0);
      nn[0][hc] = __builtin_amdgcn_mfma_f32_16x16x32_bf16(a[0][k], b2, nn[0][hc], 0, 0, 0);
      nn[1][hc] = __builtin_amdgcn_mfma_f32_16x16x32_bf16(a[1][k], b2, nn[1][hc], 0, 0, 0);
    }
  }
}

// grid: 384 blocks = cd(6) x mt(8) x ht(8); 128 threads (2 waves).
__global__ __launch_bounds__(128, 2) void k_stage(int s, StageParams P) {
  __shared__ u16 AsS[2][64 * 64];    // [rows 64][BK 64] x dbuf   (16 KB)
  __shared__ u16 BsS[2][192 * 64];   // [gaterows 192][BK 64] x dbuf (48 KB)

  int bid = blockIdx.x;
  int ht = bid & 7;
  int mt = (bid >> 3) & 7;
  int cd = bid >> 6;             // 0..5
  int dir = cd / 3, cell = cd % 3;
  int t = s - cell;
  if (t < 0 || t >= TT) return;

  int p = s & 1;  // read parity
  const float* hf_in  = p ? P.hf1 : P.hf0;
  float*       hf_out = p ? P.hf0 : P.hf1;
  const u16*   hb_in  = p ? P.hb1 : P.hb0;
  u16*         hb_out = p ? P.hb0 : P.hb1;

  int lane = threadIdx.x & 63;
  int w = threadIdx.x >> 6;      // 0..1
  int wu = __builtin_amdgcn_readfirstlane(w);   // force SGPR (wave-uniform)
  int am = lane & 15;
  int kq = lane >> 4;            // 0..3
  int slot = dir * 3 + cell;
  int hcol0 = ht * 64;
  int row0g = mt * 64;

  // operand bases (row offset mt*64 folded into A pointers)
  const char* Ah_ = (const char*)(hb_in + (size_t)slot * BB * HH + (size_t)row0g * HH);
  const char* Ax_; size_t ldax2; const char* Bx_; size_t ldbx2;
  if (cell == 0) {
    int tx = dir ? (TT - 1 - t) : t;
    Ax_ = (const char*)(P.Xb + ((size_t)tx * BB + row0g) * DP); ldax2 = DP * 2;
    Bx_ = (const char*)(P.Wih0b + (size_t)dir * G3 * DP);       ldbx2 = DP * 2;
  } else {
    Ax_ = (const char*)(hb_in + (size_t)(slot - 1) * BB * HH + (size_t)row0g * HH); ldax2 = HH * 2;
    Bx_ = (const char*)(P.Wihb + (size_t)(dir * 2 + cell - 1) * G3 * HH);           ldbx2 = HH * 2;
  }
  const char* Bh_ = (const char*)((cell == 0) ? (P.Whh0b + (size_t)dir * G3 * HH)
                                              : (P.Whhb + (size_t)(dir * 2 + cell - 1) * G3 * HH));

  int nxc = (cell == 0) ? 5 : 8;    // x-seg K64 chunks (320 or 512)
  int NC = 8 + nxc;

  // Stage chunk ci into LDS buffer pb. LDS dest is WAVE-UNIFORM (ub from
  // compile-time j and SGPR wu); lane l supplies the global address of the
  // element that lands at dest + l*16 (HW semantics of global_load_lds).
  auto stage = [&](int ci, int pb) {
    const char* Ag; size_t la2; const char* Bg; size_t lb2; int kcb;
    if (ci < 8) { Ag = Ah_; la2 = HH * 2; Bg = Bh_; lb2 = HH * 2; kcb = ci * 128; }
    else        { Ag = Ax_; la2 = ldax2;  Bg = Bx_;  lb2 = ldbx2;  kcb = (ci - 8) * 128; }
    u16* Ad = &AsS[pb][0];
    u16* Bd = &BsS[pb][0];
    #pragma unroll
    for (int j = 0; j < 4; ++j) {          // A: 512 16B units
      int ub = j * 128 + wu * 64;          // uniform
      int u = ub + lane;
      int row = u >> 3, sl = u & 7;
      int scol = ((sl ^ (row & 7)) << 4);
      gld_lds16((const u16*)(Ag + (size_t)row * la2 + kcb + scol), Ad + ub * 8);
    }
    #pragma unroll
    for (int j = 0; j < 12; ++j) {         // B: 1536 16B units (192 rows)
      int ub = j * 128 + wu * 64;          // uniform
      int u = ub + lane;
      int g = u >> 9, rr = (u >> 3) & 63, sl = u & 7;
      int scol = ((sl ^ (rr & 7)) << 4);
      gld_lds16((const u16*)(Bg + (size_t)(g * HH + hcol0 + rr) * lb2 + kcb + scol),
                Bd + ub * 8);
    }
  };

  f32x4 rs[2][4] = {}, zs[2][4] = {}, nx[2][4] = {}, nh[2][4] = {};

  stage(0, 0);
  __syncthreads();
  int cur = 0;
  for (int ci = 0; ci < NC; ++ci) {
    if (ci + 1 < NC) stage(ci + 1, cur ^ 1);
    if (ci < 8) do_chunk(&AsS[cur][0], &BsS[cur][0], w, am, kq, rs, zs, nh);
    else        do_chunk(&AsS[cur][0], &BsS[cur][0], w, am, kq, rs, zs, nx);
    __syncthreads();   // drains vmcnt(0): chunk ci+1's loads have landed
    cur ^= 1;
  }

  // gates + state update (fp32)
  const float* bihp = P.bih[slot];
  const float* bhhp = P.bhh[slot];
  const float* hin  = hf_in  + (size_t)slot * BB * HH;
  float*       hout = hf_out + (size_t)slot * BB * HH;
  u16*         bout = hb_out + (size_t)slot * BB * HH;

  #pragma unroll
  for (int hc = 0; hc < 4; ++hc) {
    int col = hcol0 + hc * 16 + am;
    float bir = bihp[col],          bhr = bhhp[col];
    float biz = bihp[HH + col],     bhz = bhhp[HH + col];
    float bin = bihp[2 * HH + col], bhn = bhhp[2 * HH + col];
    #pragma unroll
    for (int fr = 0; fr < 2; ++fr) {
      #pragma unroll
      for (int reg = 0; reg < 4; ++reg) {
        int row = row0g + w * 32 + fr * 16 + kq * 4 + reg;
        float rg = 1.f / (1.f + __expf(-(rs[fr][hc][reg] + bir + bhr)));
        float zg = 1.f / (1.f + __expf(-(zs[fr][hc][reg] + biz + bhz)));
        float ng = tanhf(nx[fr][hc][reg] + bin + rg * (nh[fr][hc][reg] + bhn));
        float hp = hin[(size_t)row * HH + col];
        float hv = (1.f - zg) * ng + zg * hp;
        hout[(size_t)row * HH + col] = hv;
        bout[(size_t)row * HH + col] = f2b(hv);
      }
    }
  }
}

struct HeadParams {
  const u16* Wmub;   // [HH][2*HH] bf16
  const u16* Wlvb;
  const u16* hb0;    // final states live in parity-0 buffer (stage 129 writes it)
  const float* bmu; const float* blv;
  float* out;        // [2][BB][HH]: mu then logvar
};

// grid: 128 blocks = which(2) x rowtile(8) x coltile(8)
__global__ __launch_bounds__(256, 2) void k_head(HeadParams P) {
  int bid = blockIdx.x;
  int ct = bid & 7, rt = (bid >> 3) & 7, which = bid >> 6;
  int lane = threadIdx.x & 63, w = threadIdx.x >> 6;
  int rbase = rt * 64 + w * 16, cbase = ct * 64;
  const u16* Wb = which ? P.Wlvb : P.Wmub;
  const float* bias = which ? P.blv : P.bmu;
  const u16* Afw = P.hb0 + (size_t)2 * BB * HH;   // slot 2 = fw layer2
  const u16* Abw = P.hb0 + (size_t)5 * BB * HH;   // slot 5 = bw layer2
  int am = lane & 15, koff = (lane >> 4) * 8;
  f32x4 acc[4] = {};
  const u16* a0 = Afw + (size_t)(rbase + am) * HH + koff;
  const u16* a1 = Abw + (size_t)(rbase + am) * HH + koff;
  #pragma unroll 1
  for (int kc = 0; kc < HH; kc += 32) {
    bf16x8 a = *(const bf16x8*)(a0 + kc);
    #pragma unroll
    for (int c = 0; c < 4; ++c) {
      int n = cbase + c * 16 + am;
      bf16x8 b = *(const bf16x8*)(Wb + (size_t)n * (2 * HH) + koff + kc);
      acc[c] = __builtin_amdgcn_mfma_f32_16x16x32_bf16(a, b, acc[c], 0, 0, 0);
    }
  }
  #pragma unroll 1
  for (int kc = 0; kc < HH; kc += 32) {
    bf16x8 a = *(const bf16x8*)(a1 + kc);
    #pragma unroll
    for (int c = 0; c < 4; ++c) {
      int n = cbase + c * 16 + am;
      bf16x8 b = *(const bf16x8*)(Wb + (size_t)n * (2 * HH) + HH + koff + kc);
      acc[c] = __builtin_amdgcn_mfma_f32_16x16x32_bf16(a, b, acc[c], 0, 0, 0);
    }
  }
  float* out = P.out + (size_t)which * BB * HH;
  int r0 = rbase + (lane >> 4) * 4;
  #pragma unroll
  for (int c = 0; c < 4; ++c) {
    int col = cbase + c * 16 + am;
    float bv = bias[col];
    #pragma unroll
    for (int reg = 0; reg < 4; ++reg) {
      out[(size_t)(r0 + reg) * HH + col] = acc[c][reg] + bv;
    }
  }
}

extern "C" void kernel_launch(void* const* d_in, const int* in_sizes, int n_in,
                              void* d_out, int out_size, void* d_ws, size_t ws_size,
                              hipStream_t stream) {
  (void)in_sizes; (void)n_in; (void)ws_size;
  char* ws = (char*)d_ws;
  size_t off = 0;
  auto alloc = [&](size_t bytes) {
    char* q = ws + off;
    off += (bytes + 255) & ~(size_t)255;
    return q;
  };
  u16* Xb    = (u16*)alloc((size_t)TT * BB * DP * 2);
  u16* Wih0b = (u16*)alloc((size_t)2 * G3 * DP * 2);
  u16* Whh0b = (u16*)alloc((size_t)2 * G3 * HH * 2);
  u16* Wihb  = (u16*)alloc((size_t)4 * G3 * HH * 2);
  u16* Whhb  = (u16*)alloc((size_t)4 * G3 * HH * 2);
  u16* Wmub  = (u16*)alloc((size_t)HH * 2 * HH * 2);
  u16* Wlvb  = (u16*)alloc((size_t)HH * 2 * HH * 2);
  float* hf  = (float*)alloc((size_t)2 * 6 * BB * HH * 4);
  u16*   hb  = (u16*)alloc((size_t)2 * 6 * BB * HH * 2);

  const float* X = (const float*)d_in[0];

  hipMemsetAsync(hf, 0, (size_t)2 * 6 * BB * HH * 4, stream);
  hipMemsetAsync(hb, 0, (size_t)2 * 6 * BB * HH * 2, stream);

  {
    int n = TT * BB * DP;
    k_cvt_pad<<<(n + 255) / 256, 256, 0, stream>>>(X, Xb, TT * BB, DD, DP);
    int nw0 = G3 * DP;
    k_cvt_pad<<<(nw0 + 255) / 256, 256, 0, stream>>>((const float*)d_in[2],  Wih0b,                   G3, DD, DP);
    k_cvt_pad<<<(nw0 + 255) / 256, 256, 0, stream>>>((const float*)d_in[10], Wih0b + (size_t)G3 * DP, G3, DD, DP);
    int n1 = G3 * HH;
    k_cvt<<<(n1 + 255) / 256, 256, 0, stream>>>((const float*)d_in[3],  Whh0b,      n1);
    k_cvt<<<(n1 + 255) / 256, 256, 0, stream>>>((const float*)d_in[11], Whh0b + n1, n1);
    int n2 = 2 * G3 * HH;
    k_cvt<<<(n2 + 255) / 256, 256, 0, stream>>>((const float*)d_in[6],  Wihb,      n2);
    k_cvt<<<(n2 + 255) / 256, 256, 0, stream>>>((const float*)d_in[14], Wihb + n2, n2);
    k_cvt<<<(n2 + 255) / 256, 256, 0, stream>>>((const float*)d_in[7],  Whhb,      n2);
    k_cvt<<<(n2 + 255) / 256, 256, 0, stream>>>((const float*)d_in[15], Whhb + n2, n2);
    int n3 = HH * 2 * HH;
    k_cvt<<<(n3 + 255) / 256, 256, 0, stream>>>((const float*)d_in[18], Wmub, n3);
    k_cvt<<<(n3 + 255) / 256, 256, 0, stream>>>((const float*)d_in[20], Wlvb, n3);
  }

  StageParams SP;
  SP.Xb = Xb; SP.Wih0b = Wih0b; SP.Whh0b = Whh0b; SP.Wihb = Wihb; SP.Whhb = Whhb;
  SP.hf0 = hf;                       SP.hf1 = hf + (size_t)6 * BB * HH;
  SP.hb0 = hb;                       SP.hb1 = hb + (size_t)6 * BB * HH;
  SP.bih[0] = (const float*)d_in[4];
  SP.bih[1] = (const float*)d_in[8];
  SP.bih[2] = (const float*)d_in[8] + G3;
  SP.bih[3] = (const float*)d_in[12];
  SP.bih[4] = (const float*)d_in[16];
  SP.bih[5] = (const float*)d_in[16] + G3;
  SP.bhh[0] = (const float*)d_in[5];
  SP.bhh[1] = (const float*)d_in[9];
  SP.bhh[2] = (const float*)d_in[9] + G3;
  SP.bhh[3] = (const float*)d_in[13];
  SP.bhh[4] = (const float*)d_in[17];
  SP.bhh[5] = (const float*)d_in[17] + G3;

  for (int s = 0; s < NSTAGE; ++s) {
    k_stage<<<384, 128, 0, stream>>>(s, SP);
  }

  HeadParams HP;
  HP.Wmub = Wmub; HP.Wlvb = Wlvb; HP.hb0 = hb;
  HP.bmu = (const float*)d_in[19]; HP.blv = (const float*)d_in[21];
  HP.out = (float*)d_out;
  k_head<<<128, 256, 0, stream>>>(HP);
}